// Round 13
// baseline (23.441 us; speedup 1.0000x reference)
//
#include <hip/hip_runtime.h>
#include <cstdint>
#include <cstddef>
#include <algorithm>

// ---------------- problem constants ----------------
#define NROW 16      // only bn rows 0..15 feed the outputs (n=16)
#define CTOT 384
#define HW   1024    // 32*32
#define KSEL 20
#define PSEL 96
#define NREM 76      // P - K
#define NUNSEL 1004  // HW - K

#define CPB   8                  // channels per block (kernel A)
#define SPLIT (CTOT / CPB)       // 48
#define PLW   1040               // padded LDS plane stride (floats): 4 bands * 260
#define NSLC  16                 // 64-px slices per image (kernel B)
#define NCAND (NSLC * KSEL)      // 320 candidates per image

typedef unsigned long long u64;

struct Perm76 { int p[NREM]; };

// ---------------- kernel A: zero-over-read shuffle-conv -> partial planes (R12-proven) ----------------
// grid = NROW*SPLIT (768) blocks x 256t = 3 blocks/CU. Block (r,s): wave w, half owns channel
// s*8+2w+half. Lane h<32: band b=h>>3 (rows 8b..8b+7), colgrp c=h&7. Every feature element
// loaded exactly once (halos via shfl).
__global__ __launch_bounds__(256) void pv_conv(
    const float* __restrict__ feat, const float* __restrict__ dw_w,
    const float* __restrict__ pw_w, float* __restrict__ partial,
    int* __restrict__ ticket)
{
  __shared__ float red[8 * PLW];                // 33,280 B
  const int t = threadIdx.x;
  const int w = t >> 6, lane = t & 63;
  const int h = lane & 31, hb = lane & 32;      // half-lane idx, half selector bit
  const int b = h >> 3, c = h & 7;
  const int r = blockIdx.x & (NROW - 1);
  const int s = blockIdx.x >> 4;

  if (s == 0 && t == 0) ticket[r] = 0;          // visible to kernel B at kernel boundary

  const int ch = s * CPB + 2 * w + (lane >> 5);
  const float* base = feat + ((size_t)r * CTOT + ch) * HW + 4 * c;

  // 8 own rows, each element of the plane loaded exactly once across the block
  float4 f[8];
  #pragma unroll
  for (int j = 0; j < 8; ++j)
    f[j] = *reinterpret_cast<const float4*>(base + (8 * b + j) * 32);

  // fused weights (half-wave-uniform)
  float w9[9];
  {
    const float pw = pw_w[ch];
    #pragma unroll
    for (int i = 0; i < 9; ++i) w9[i] = dw_w[ch * 9 + i] * pw;
  }

  // halo rows via shfl from lanes +-8 (band edges -> zero)
  const int sm = hb | ((h - 8) & 31), sp = hb | ((h + 8) & 31);
  float4 fm, fp;
  fm.x = __shfl(f[7].x, sm); fm.y = __shfl(f[7].y, sm);
  fm.z = __shfl(f[7].z, sm); fm.w = __shfl(f[7].w, sm);
  fp.x = __shfl(f[0].x, sp); fp.y = __shfl(f[0].y, sp);
  fp.z = __shfl(f[0].z, sp); fp.w = __shfl(f[0].w, sp);
  if (b == 0) { fm.x = 0.f; fm.y = 0.f; fm.z = 0.f; fm.w = 0.f; }
  if (b == 3) { fp.x = 0.f; fp.y = 0.f; fp.z = 0.f; fp.w = 0.f; }

  // halo cols: L[k]/R[k] for the 10-row sequence k=0..9 (row 8b-1+k)
  float L[10], R[10];
  #pragma unroll
  for (int k = 1; k <= 8; ++k) {
    L[k] = __shfl(f[k - 1].w, hb | ((h - 1) & 31));
    R[k] = __shfl(f[k - 1].x, hb | ((h + 1) & 31));
  }
  L[0] = __shfl(f[7].w, hb | ((h - 9) & 31));
  R[0] = __shfl(f[7].x, hb | ((h - 7) & 31));
  L[9] = __shfl(f[0].w, hb | ((h + 7) & 31));
  R[9] = __shfl(f[0].x, hb | ((h + 9) & 31));
  if (b == 0) { L[0] = 0.f; R[0] = 0.f; }
  if (b == 3) { L[9] = 0.f; R[9] = 0.f; }
  if (c == 0) {
    #pragma unroll
    for (int k = 0; k < 10; ++k) L[k] = 0.f;
  }
  if (c == 7) {
    #pragma unroll
    for (int k = 0; k < 10; ++k) R[k] = 0.f;
  }

  // conv: out rows j=0..7, kernel rows d=0..2 read seq row k=j+d
  float acc[8][4];
  #pragma unroll
  for (int j = 0; j < 8; ++j)
    #pragma unroll
    for (int k = 0; k < 4; ++k) acc[j][k] = 0.f;

  #pragma unroll
  for (int j = 0; j < 8; ++j) {
    #pragma unroll
    for (int d = 0; d < 3; ++d) {
      const int k = j + d;
      const float4 C = (k == 0) ? fm : (k == 9 ? fp : f[k - 1]);
      const float a0 = L[k], a1 = C.x, a2 = C.y, a3 = C.z, a4 = C.w, a5 = R[k];
      const float t0 = w9[3 * d], t1 = w9[3 * d + 1], t2 = w9[3 * d + 2];
      acc[j][0] += a0 * t0 + a1 * t1 + a2 * t2;
      acc[j][1] += a1 * t0 + a2 * t1 + a3 * t2;
      acc[j][2] += a2 * t0 + a3 * t1 + a4 * t2;
      acc[j][3] += a3 * t0 + a4 * t1 + a5 * t2;
    }
  }

  // park per-channel plane in LDS (+4-float band padding kills 4-way conflicts)
  {
    float* pl = &red[(2 * w + (lane >> 5)) * PLW + b * 260 + 4 * c];
    #pragma unroll
    for (int j = 0; j < 8; ++j)
      *reinterpret_cast<float4*>(pl + j * 32) =
          make_float4(acc[j][0], acc[j][1], acc[j][2], acc[j][3]);
  }
  __syncthreads();

  // block reduce 8 channel planes -> partial plane (float4, coalesced)
  {
    const int row = t >> 3;
    const int off = (row >> 3) * 260 + (row & 7) * 32 + 4 * (t & 7);
    float4 sum = make_float4(0.f, 0.f, 0.f, 0.f);
    #pragma unroll
    for (int p = 0; p < 8; ++p) {
      const float4 v = *reinterpret_cast<const float4*>(&red[p * PLW + off]);
      sum.x += v.x; sum.y += v.y; sum.z += v.z; sum.w += v.w;
    }
    *reinterpret_cast<float4*>(partial + ((size_t)(r * SPLIT + s)) * HW + 4 * t) = sum;
  }
}

// ---------------- kernel B: 64-px slice reduce+top20 + atomic ticket + finisher select ----------------
// grid = 256 blocks (16 slices per image) x 256t. Each block publishes 20 u64 keys via atomicExch;
// the 16th arriver per image runs the select and emits. No fences (R5 lesson): producer exchanges
// are drained before the ticket atomic; all transfers go through the device-coherent atomic point.
__global__ __launch_bounds__(256) void pv_reduceSelect(
    const float* __restrict__ partial, u64* __restrict__ cand,
    int* __restrict__ ticket, int* __restrict__ out, Perm76 perm)
{
  __shared__ float red[16][64];
  __shared__ u64 keysh[64];
  __shared__ u64 candL[NCAND];
  __shared__ int votes[KSEL];
  __shared__ int maskv[HW];
  __shared__ int wsumS[4];
  __shared__ int unsel[NUNSEL];
  __shared__ int isFinS;

  const int r = blockIdx.x >> 4;
  const int q = blockIdx.x & 15;
  const int t = threadIdx.x;
  const int sg = t >> 4, l16 = t & 15;

  // phase 1: group sg reduces planes sg, sg+16, sg+32 over its 64-px slice (float4 coalesced)
  const float* bp = partial + ((size_t)(r * SPLIT + sg)) * HW + q * 64 + 4 * l16;
  float4 a = make_float4(0.f, 0.f, 0.f, 0.f);
  #pragma unroll
  for (int i = 0; i < 3; ++i) {
    const float4 v = *reinterpret_cast<const float4*>(bp + (size_t)(16 * i) * HW);
    a.x += v.x; a.y += v.y; a.z += v.z; a.w += v.w;
  }
  *reinterpret_cast<float4*>(&red[sg][4 * l16]) = a;
  __syncthreads();

  if (t < 64) {
    float sc = 0.f;
    #pragma unroll
    for (int g = 0; g < 16; ++g) sc += red[g][t];
    const uint32_t bb = __float_as_uint(sc);
    const uint32_t mm = (bb & 0x80000000u) ? ~bb : (bb | 0x80000000u);
    const int gpx = q * 64 + t;
    keysh[t] = ((u64)mm << 32) | (uint32_t)(1023 - gpx);  // larger wins; tie -> smaller idx
  }
  __syncthreads();
  if (t < 64) {
    const u64 my = keysh[t];
    int rank = 0;
    #pragma unroll
    for (int j = 0; j < 64; ++j) rank += (keysh[j] > my);  // broadcast reads, unique keys
    if (rank < KSEL)
      atomicExch(&cand[((size_t)(r * NSLC + q)) * KSEL + rank], my);  // device-coherent publish
  }
  __syncthreads();                     // drains vmcnt: all exchanges complete before ticket

  if (t == 0) isFinS = (atomicAdd(&ticket[r], 1) == NSLC - 1);
  __syncthreads();
  if (!isFinS) return;

  // ---- finisher: global top-20 from 320 candidates, selection, emit ----
  candL[t] = atomicAdd(&cand[(size_t)r * NCAND + t], 0ull);
  if (t < NCAND - 256) candL[256 + t] = atomicAdd(&cand[(size_t)r * NCAND + 256 + t], 0ull);
  maskv[t] = 0; maskv[t + 256] = 0; maskv[t + 512] = 0; maskv[t + 768] = 0;
  __syncthreads();

  // exact global top-20 (union of slice top-20s contains it)
  {
    const u64 my0 = candL[t];
    int rk0 = 0;
    for (int j = 0; j < NCAND; ++j) rk0 += (candL[j] > my0);
    if (rk0 < KSEL) votes[rk0] = 1023 - (int)(my0 & 1023ull);
    if (t < NCAND - 256) {
      const u64 my1 = candL[256 + t];
      int rk1 = 0;
      for (int j = 0; j < NCAND; ++j) rk1 += (candL[j] > my1);
      if (rk1 < KSEL) votes[rk1] = 1023 - (int)(my1 & 1023ull);
    }
  }
  __syncthreads();

  // selected coords + mask
  if (t < KSEL) {
    const int idx = votes[t];
    maskv[idx] = 1;
    int xx = idx & 31, yy = idx >> 5;
    if (xx < 1) xx = 1;                      // clip(.,1,31); upper bound can't trigger
    if (yy < 1) yy = 1;
    out[r * PSEL + t]               = xx;
    out[NROW * PSEL + r * PSEL + t] = yy;
  }
  __syncthreads();

  // unselected indices ascending via shfl prefix over !mask
  const int lane = t & 63, wv = t >> 6;
  int cnt = 0;
  #pragma unroll
  for (int j = 0; j < 4; ++j) cnt += (maskv[t * 4 + j] == 0);
  int inc = cnt;
  #pragma unroll
  for (int dd = 1; dd < 64; dd <<= 1) {
    const int o = __shfl_up(inc, dd);
    if (lane >= dd) inc += o;
  }
  if (lane == 63) wsumS[wv] = inc;
  __syncthreads();
  int basep = 0;
  for (int i = 0; i < 4; ++i) if (i < wv) basep += wsumS[i];
  int pos = basep + inc - cnt;               // exclusive prefix
  #pragma unroll
  for (int j = 0; j < 4; ++j) {
    const int i = t * 4 + j;
    if (!maskv[i]) unsel[pos++] = i;
  }
  __syncthreads();

  // random remaining via fixed permutation
  if (t < NREM) {
    const int u = unsel[perm.p[t]];
    int xx = u & 31, yy = u >> 5;
    if (xx < 1) xx = 1;
    if (yy < 1) yy = 1;
    out[r * PSEL + KSEL + t]               = xx;
    out[NROW * PSEL + r * PSEL + KSEL + t] = yy;
  }
}

// ---------------- host: JAX threefry2x32 (partitionable) ----------------
static inline uint32_t rotl32(uint32_t v, uint32_t n) { return (v << n) | (v >> (32 - n)); }

static void tf2x32(uint32_t k0, uint32_t k1, uint32_t x0, uint32_t x1,
                   uint32_t* o0, uint32_t* o1)
{
  const uint32_t ks[3] = { k0, k1, k0 ^ k1 ^ 0x1BD11BDAu };
  static const uint32_t rot[2][4] = { {13, 15, 26, 6}, {17, 29, 16, 24} };
  x0 += ks[0]; x1 += ks[1];
  for (int i = 0; i < 5; ++i) {
    const uint32_t* rr = rot[i & 1];
    for (int j = 0; j < 4; ++j) { x0 += x1; x1 = rotl32(x1, rr[j]); x1 ^= x0; }
    x0 += ks[(i + 1) % 3];
    x1 += ks[(i + 2) % 3] + (uint32_t)(i + 1);
  }
  *o0 = x0; *o1 = x1;
}

// perm = jax.random.permutation(jax.random.key(42), 1004)[:76]  (threefry_partitionable)
static void compute_perm(int* perm_out)
{
  uint32_t bits[NUNSEL];
  uint32_t sk0, sk1;
  { uint32_t o0, o1; tf2x32(0u, 42u, 0u, 1u, &o0, &o1); sk0 = o0; sk1 = o1; }
  for (int i = 0; i < NUNSEL; ++i) {
    uint32_t o0, o1; tf2x32(sk0, sk1, 0u, (uint32_t)i, &o0, &o1);
    bits[i] = o0 ^ o1;
  }
  int idx[NUNSEL];
  for (int i = 0; i < NUNSEL; ++i) idx[i] = i;
  std::stable_sort(idx, idx + NUNSEL, [&](int a, int b) { return bits[a] < bits[b]; });
  for (int j = 0; j < NREM; ++j) perm_out[j] = idx[j];
}

extern "C" void kernel_launch(void* const* d_in, const int* in_sizes, int n_in,
                              void* d_out, int out_size, void* d_ws, size_t ws_size,
                              hipStream_t stream)
{
  (void)in_sizes; (void)n_in; (void)out_size; (void)ws_size;
  const float* feat = (const float*)d_in[0];
  const float* dw_w = (const float*)d_in[1];
  // d_in[2] = dw_b (zeros; constant shift, ordering-irrelevant)
  const float* pw_w = (const float*)d_in[3];
  // d_in[4] = pw_b (constant shift, ordering-irrelevant)
  int*   out     = (int*)d_out;
  float* partial = (float*)d_ws;                                // 16*48*4 KB = 3 MB
  u64*   cand    = (u64*)((char*)d_ws + (size_t)NROW * SPLIT * HW * sizeof(float)); // 16*320 u64
  int*   ticket  = (int*)(cand + (size_t)NROW * NCAND);         // 16 ints, zeroed by kernel A

  Perm76 perm;
  compute_perm(perm.p);                      // deterministic host compute, kernel-arg baked

  pv_conv<<<NROW * SPLIT, 256, 0, stream>>>(feat, dw_w, pw_w, partial, ticket);
  pv_reduceSelect<<<256, 256, 0, stream>>>(partial, cand, ticket, out, perm);
}

// Round 14
// 17.490 us; speedup vs baseline: 1.3403x; 1.3403x over previous
//
#include <hip/hip_runtime.h>
#include <cstdint>
#include <cstddef>
#include <algorithm>

// ---------------- problem constants ----------------
#define NROW 16      // only bn rows 0..15 feed the outputs (n=16)
#define CTOT 384
#define HW   1024    // 32*32
#define KSEL 20
#define PSEL 96
#define NREM 76      // P - K
#define NUNSEL 1004  // HW - K

#define CPB   8                  // channels per block (kernel A)
#define SPLIT (CTOT / CPB)       // 48
#define PLW   1040               // padded LDS plane stride (floats): 4 bands * 260

typedef unsigned long long u64;

struct Perm76 { int p[NREM]; };

// ---------------- kernel A: zero-over-read shuffle-conv -> partial planes (R12-proven) ----------------
// grid = NROW*SPLIT (768) blocks x 256t = 3 blocks/CU. Block (r,s): wave w, half owns channel
// s*8+2w+half. Lane h<32: band b=h>>3 (rows 8b..8b+7), colgrp c=h&7. Every feature element
// loaded exactly once (halos via shfl).
__global__ __launch_bounds__(256) void pv_conv(
    const float* __restrict__ feat, const float* __restrict__ dw_w,
    const float* __restrict__ pw_w, float* __restrict__ partial,
    int* __restrict__ ticket)
{
  __shared__ float red[8 * PLW];                // 33,280 B
  const int t = threadIdx.x;
  const int w = t >> 6, lane = t & 63;
  const int h = lane & 31, hb = lane & 32;      // half-lane idx, half selector bit
  const int b = h >> 3, c = h & 7;
  const int r = blockIdx.x & (NROW - 1);
  const int s = blockIdx.x >> 4;

  if (s == 0 && t == 0) ticket[r] = 0;          // visible to kernel B at kernel boundary

  const int ch = s * CPB + 2 * w + (lane >> 5);
  const float* base = feat + ((size_t)r * CTOT + ch) * HW + 4 * c;

  // 8 own rows, each element of the plane loaded exactly once across the block
  float4 f[8];
  #pragma unroll
  for (int j = 0; j < 8; ++j)
    f[j] = *reinterpret_cast<const float4*>(base + (8 * b + j) * 32);

  // fused weights (half-wave-uniform)
  float w9[9];
  {
    const float pw = pw_w[ch];
    #pragma unroll
    for (int i = 0; i < 9; ++i) w9[i] = dw_w[ch * 9 + i] * pw;
  }

  // halo rows via shfl from lanes +-8 (band edges -> zero)
  const int sm = hb | ((h - 8) & 31), sp = hb | ((h + 8) & 31);
  float4 fm, fp;
  fm.x = __shfl(f[7].x, sm); fm.y = __shfl(f[7].y, sm);
  fm.z = __shfl(f[7].z, sm); fm.w = __shfl(f[7].w, sm);
  fp.x = __shfl(f[0].x, sp); fp.y = __shfl(f[0].y, sp);
  fp.z = __shfl(f[0].z, sp); fp.w = __shfl(f[0].w, sp);
  if (b == 0) { fm.x = 0.f; fm.y = 0.f; fm.z = 0.f; fm.w = 0.f; }
  if (b == 3) { fp.x = 0.f; fp.y = 0.f; fp.z = 0.f; fp.w = 0.f; }

  // halo cols: L[k]/R[k] for the 10-row sequence k=0..9 (row 8b-1+k)
  float L[10], R[10];
  #pragma unroll
  for (int k = 1; k <= 8; ++k) {
    L[k] = __shfl(f[k - 1].w, hb | ((h - 1) & 31));
    R[k] = __shfl(f[k - 1].x, hb | ((h + 1) & 31));
  }
  L[0] = __shfl(f[7].w, hb | ((h - 9) & 31));
  R[0] = __shfl(f[7].x, hb | ((h - 7) & 31));
  L[9] = __shfl(f[0].w, hb | ((h + 7) & 31));
  R[9] = __shfl(f[0].x, hb | ((h + 9) & 31));
  if (b == 0) { L[0] = 0.f; R[0] = 0.f; }
  if (b == 3) { L[9] = 0.f; R[9] = 0.f; }
  if (c == 0) {
    #pragma unroll
    for (int k = 0; k < 10; ++k) L[k] = 0.f;
  }
  if (c == 7) {
    #pragma unroll
    for (int k = 0; k < 10; ++k) R[k] = 0.f;
  }

  // conv: out rows j=0..7, kernel rows d=0..2 read seq row k=j+d
  float acc[8][4];
  #pragma unroll
  for (int j = 0; j < 8; ++j)
    #pragma unroll
    for (int k = 0; k < 4; ++k) acc[j][k] = 0.f;

  #pragma unroll
  for (int j = 0; j < 8; ++j) {
    #pragma unroll
    for (int d = 0; d < 3; ++d) {
      const int k = j + d;
      const float4 C = (k == 0) ? fm : (k == 9 ? fp : f[k - 1]);
      const float a0 = L[k], a1 = C.x, a2 = C.y, a3 = C.z, a4 = C.w, a5 = R[k];
      const float t0 = w9[3 * d], t1 = w9[3 * d + 1], t2 = w9[3 * d + 2];
      acc[j][0] += a0 * t0 + a1 * t1 + a2 * t2;
      acc[j][1] += a1 * t0 + a2 * t1 + a3 * t2;
      acc[j][2] += a2 * t0 + a3 * t1 + a4 * t2;
      acc[j][3] += a3 * t0 + a4 * t1 + a5 * t2;
    }
  }

  // park per-channel plane in LDS (+4-float band padding kills 4-way conflicts)
  {
    float* pl = &red[(2 * w + (lane >> 5)) * PLW + b * 260 + 4 * c];
    #pragma unroll
    for (int j = 0; j < 8; ++j)
      *reinterpret_cast<float4*>(pl + j * 32) =
          make_float4(acc[j][0], acc[j][1], acc[j][2], acc[j][3]);
  }
  __syncthreads();

  // block reduce 8 channel planes -> partial plane (float4, coalesced)
  {
    const int row = t >> 3;
    const int off = (row >> 3) * 260 + (row & 7) * 32 + 4 * (t & 7);
    float4 sum = make_float4(0.f, 0.f, 0.f, 0.f);
    #pragma unroll
    for (int p = 0; p < 8; ++p) {
      const float4 v = *reinterpret_cast<const float4*>(&red[p * PLW + off]);
      sum.x += v.x; sum.y += v.y; sum.z += v.z; sum.w += v.w;
    }
    *reinterpret_cast<float4*>(partial + ((size_t)(r * SPLIT + s)) * HW + 4 * t) = sum;
  }
}

// ---------------- kernel B: slice reduce+top20 + atomic ticket + finisher select (R11/R12-proven) ----------------
__global__ __launch_bounds__(256) void pv_reduceSelect(
    const float* __restrict__ partial, u64* __restrict__ cand,
    int* __restrict__ ticket, int* __restrict__ out, Perm76 perm)
{
  __shared__ float red[8][128];
  __shared__ u64 keysh[128];
  __shared__ u64 candL[8 * KSEL];
  __shared__ int votes[KSEL];
  __shared__ int maskv[HW];
  __shared__ int wsumS[4];
  __shared__ int unsel[NUNSEL];
  __shared__ int isFinS;

  const int r = blockIdx.x >> 3;
  const int q = blockIdx.x & 7;
  const int t = threadIdx.x;
  const int sg = t >> 5, l32 = t & 31;

  // group sg reduces planes sg, sg+8, ..., sg+40 over the 128-px slice
  const float* bp = partial + ((size_t)(r * SPLIT + sg)) * HW + q * 128 + 4 * l32;
  float4 a = make_float4(0.f, 0.f, 0.f, 0.f);
  #pragma unroll
  for (int i = 0; i < 6; ++i) {
    const float4 v = *reinterpret_cast<const float4*>(bp + (size_t)(8 * i) * HW);
    a.x += v.x; a.y += v.y; a.z += v.z; a.w += v.w;
  }
  *reinterpret_cast<float4*>(&red[sg][4 * l32]) = a;
  __syncthreads();

  if (t < 128) {
    float sc = 0.f;
    #pragma unroll
    for (int g = 0; g < 8; ++g) sc += red[g][t];
    const uint32_t bb = __float_as_uint(sc);
    const uint32_t mm = (bb & 0x80000000u) ? ~bb : (bb | 0x80000000u);
    const int gpx = q * 128 + t;
    keysh[t] = ((u64)mm << 32) | (uint32_t)(1023 - gpx);  // larger wins; tie -> smaller idx
  }
  __syncthreads();
  if (t < 128) {
    const u64 my = keysh[t];
    int rank = 0;
    for (int j = 0; j < 128; ++j) rank += (keysh[j] > my);  // broadcast reads, unique keys
    if (rank < KSEL)
      atomicExch(&cand[((size_t)(r * 8 + q)) * KSEL + rank], my);  // device-coherent publish
  }
  __syncthreads();                     // drains vmcnt: all exchanges complete before ticket

  if (t == 0) isFinS = (atomicAdd(&ticket[r], 1) == 7);
  __syncthreads();
  if (!isFinS) return;

  // ---- finisher: global top-20 from 160 candidates, selection, emit ----
  if (t < 8 * KSEL) candL[t] = atomicAdd(&cand[(size_t)r * 8 * KSEL + t], 0ull);
  maskv[t] = 0; maskv[t + 256] = 0; maskv[t + 512] = 0; maskv[t + 768] = 0;
  __syncthreads();

  if (t < 8 * KSEL) {
    const u64 my = candL[t];
    int rank = 0;
    for (int j = 0; j < 8 * KSEL; ++j) rank += (candL[j] > my);
    if (rank < KSEL) votes[rank] = 1023 - (int)(my & 1023ull);
  }
  __syncthreads();

  if (t < KSEL) {
    const int idx = votes[t];
    maskv[idx] = 1;
    int xx = idx & 31, yy = idx >> 5;
    if (xx < 1) xx = 1;                      // clip(.,1,31); upper bound can't trigger
    if (yy < 1) yy = 1;
    out[r * PSEL + t]               = xx;
    out[NROW * PSEL + r * PSEL + t] = yy;
  }
  __syncthreads();

  const int lane = t & 63, wv = t >> 6;
  int cnt = 0;
  #pragma unroll
  for (int j = 0; j < 4; ++j) cnt += (maskv[t * 4 + j] == 0);
  int inc = cnt;
  #pragma unroll
  for (int dd = 1; dd < 64; dd <<= 1) {
    const int o = __shfl_up(inc, dd);
    if (lane >= dd) inc += o;
  }
  if (lane == 63) wsumS[wv] = inc;
  __syncthreads();
  int basep = 0;
  for (int i = 0; i < 4; ++i) if (i < wv) basep += wsumS[i];
  int pos = basep + inc - cnt;               // exclusive prefix
  #pragma unroll
  for (int j = 0; j < 4; ++j) {
    const int i = t * 4 + j;
    if (!maskv[i]) unsel[pos++] = i;
  }
  __syncthreads();

  if (t < NREM) {
    const int u = unsel[perm.p[t]];
    int xx = u & 31, yy = u >> 5;
    if (xx < 1) xx = 1;
    if (yy < 1) yy = 1;
    out[r * PSEL + KSEL + t]               = xx;
    out[NROW * PSEL + r * PSEL + KSEL + t] = yy;
  }
}

// ---------------- host: JAX threefry2x32 (partitionable) ----------------
static inline uint32_t rotl32(uint32_t v, uint32_t n) { return (v << n) | (v >> (32 - n)); }

static void tf2x32(uint32_t k0, uint32_t k1, uint32_t x0, uint32_t x1,
                   uint32_t* o0, uint32_t* o1)
{
  const uint32_t ks[3] = { k0, k1, k0 ^ k1 ^ 0x1BD11BDAu };
  static const uint32_t rot[2][4] = { {13, 15, 26, 6}, {17, 29, 16, 24} };
  x0 += ks[0]; x1 += ks[1];
  for (int i = 0; i < 5; ++i) {
    const uint32_t* rr = rot[i & 1];
    for (int j = 0; j < 4; ++j) { x0 += x1; x1 = rotl32(x1, rr[j]); x1 ^= x0; }
    x0 += ks[(i + 1) % 3];
    x1 += ks[(i + 2) % 3] + (uint32_t)(i + 1);
  }
  *o0 = x0; *o1 = x1;
}

// perm = jax.random.permutation(jax.random.key(42), 1004)[:76]  (threefry_partitionable)
static void compute_perm(int* perm_out)
{
  uint32_t bits[NUNSEL];
  uint32_t sk0, sk1;
  { uint32_t o0, o1; tf2x32(0u, 42u, 0u, 1u, &o0, &o1); sk0 = o0; sk1 = o1; }
  for (int i = 0; i < NUNSEL; ++i) {
    uint32_t o0, o1; tf2x32(sk0, sk1, 0u, (uint32_t)i, &o0, &o1);
    bits[i] = o0 ^ o1;
  }
  int idx[NUNSEL];
  for (int i = 0; i < NUNSEL; ++i) idx[i] = i;
  std::stable_sort(idx, idx + NUNSEL, [&](int a, int b) { return bits[a] < bits[b]; });
  for (int j = 0; j < NREM; ++j) perm_out[j] = idx[j];
}

extern "C" void kernel_launch(void* const* d_in, const int* in_sizes, int n_in,
                              void* d_out, int out_size, void* d_ws, size_t ws_size,
                              hipStream_t stream)
{
  (void)in_sizes; (void)n_in; (void)out_size; (void)ws_size;
  const float* feat = (const float*)d_in[0];
  const float* dw_w = (const float*)d_in[1];
  // d_in[2] = dw_b (zeros; constant shift, ordering-irrelevant)
  const float* pw_w = (const float*)d_in[3];
  // d_in[4] = pw_b (constant shift, ordering-irrelevant)
  int*   out     = (int*)d_out;
  float* partial = (float*)d_ws;                                // 16*48*4 KB = 3 MB
  u64*   cand    = (u64*)((char*)d_ws + (size_t)NROW * SPLIT * HW * sizeof(float)); // 16*160 u64
  int*   ticket  = (int*)(cand + (size_t)NROW * 8 * KSEL);      // 16 ints, zeroed by kernel A

  Perm76 perm;
  compute_perm(perm.p);                      // deterministic host compute, kernel-arg baked

  pv_conv<<<NROW * SPLIT, 256, 0, stream>>>(feat, dw_w, pw_w, partial, ticket);
  pv_reduceSelect<<<128, 256, 0, stream>>>(partial, cand, ticket, out, perm);
}